// Round 4
// baseline (1169.037 us; speedup 1.0000x reference)
//
#include <hip/hip_runtime.h>

#define FI 256
#define FH 64
#define FO 128

// --- zero n floats ---
__global__ void zero_kernel(float* __restrict__ p, int n) {
    int i = blockIdx.x * 256 + threadIdx.x;
    if (i < n) p[i] = 0.f;
}

// --- zero the agg (lower-64) half of every out row ---
__global__ void zero_agg_kernel(float* __restrict__ out, int N) {
    int i = blockIdx.x * 256 + threadIdx.x;   // over N*64
    if (i >= N * FH) return;
    out[(size_t)(i >> 6) * FO + (i & 63)] = 0.f;
}

// --- degree: deg[dst] += 1 over edges ---
__global__ void deg_kernel(const int* __restrict__ dst, float* __restrict__ deg, int E) {
    int e = blockIdx.x * 256 + threadIdx.x;
    if (e < E) atomicAdd(&deg[dst[e]], 1.0f);
}

// --- dinv[i] = rsqrt(deg[i] + 1)  (in place) ---
__global__ void dinv_kernel(float* __restrict__ deg, int N) {
    int i = blockIdx.x * 256 + threadIdx.x;
    if (i < N) deg[i] = rsqrtf(deg[i] + 1.0f);
}

// --- h1 = x @ W1 -> upper half of out rows; one wave per row, lane = out col ---
__global__ void mm1_kernel(const float* __restrict__ x, const float* __restrict__ W1,
                           float* __restrict__ out, int N) {
    __shared__ float Wl[128 * FH];   // 32 KB k-chunk of W1
    int lane = threadIdx.x & 63;
    int w    = threadIdx.x >> 6;
    int row  = blockIdx.x * 4 + w;
    float acc = 0.f;
    for (int half = 0; half < 2; ++half) {
        __syncthreads();
        for (int t = threadIdx.x; t < 128 * FH; t += 256)
            Wl[t] = W1[half * 128 * FH + t];
        __syncthreads();
        if (row < N) {
            const float* xr = x + (size_t)row * FI + half * 128;
            #pragma unroll 8
            for (int k = 0; k < 128; ++k)
                acc = fmaf(xr[k], Wl[k * FH + lane], acc);   // 2 lanes/bank: free
        }
    }
    if (row < N) out[(size_t)row * FO + FH + lane] = acc;    // upper half
}

// --- edge scatter: out[d][lane] += out[s][64+lane] * dinv[s]*dinv[d]; 1 wave/edge ---
__global__ void scatter_kernel(const int* __restrict__ src, const int* __restrict__ dst,
                               const float* __restrict__ dinv, float* __restrict__ out, int E) {
    int e = blockIdx.x * 4 + (threadIdx.x >> 6);
    if (e >= E) return;
    int lane = threadIdx.x & 63;
    int s = src[e];
    int d = dst[e];
    float wgt = dinv[s] * dinv[d];
    float v = out[(size_t)s * FO + FH + lane] * wgt;   // coalesced 256B gather (upper half)
    atomicAdd(&out[(size_t)d * FO + lane], v);         // 64 contiguous atomics (lower half)
}

// --- upper = relu(lower + upper*dinv^2 + b1); lower = 0 (ready for layer 2) ---
__global__ void fuse_relu_kernel(float* __restrict__ out, const float* __restrict__ dinv,
                                 const float* __restrict__ b1, int N) {
    int i = blockIdx.x * 256 + threadIdx.x;   // over N*64
    if (i >= N * FH) return;
    int row = i >> 6;
    int c   = i & 63;
    size_t base = (size_t)row * FO;
    float s = dinv[row];
    float v = out[base + c] + out[base + FH + c] * s * s + b1[c];
    out[base + FH + c] = fmaxf(v, 0.f);
    out[base + c] = 0.f;
}

// --- out_row = (lower + upper*dinv^2) @ W2 + b2 ; in-place over both halves ---
__global__ void mm2_kernel(const float* __restrict__ dinv, const float* __restrict__ W2,
                           const float* __restrict__ b2, float* __restrict__ out, int N) {
    __shared__ float Wl[FH * FO];   // 32 KB
    for (int t = threadIdx.x; t < FH * FO; t += 256) Wl[t] = W2[t];
    __syncthreads();
    int c   = threadIdx.x & 127;
    int row = blockIdx.x * 2 + (threadIdx.x >> 7);
    bool valid = row < N;
    float acc = 0.f;
    if (valid) {
        float s = dinv[row]; s = s * s;
        const float* a = out + (size_t)row * FO;        // agg2 (lower 64)
        const float* h = a + FH;                         // hrelu (upper 64)
        acc = b2[c];
        #pragma unroll 8
        for (int j = 0; j < FH; ++j)
            acc = fmaf(a[j] + h[j] * s, Wl[j * FO + c], acc);
    }
    __syncthreads();                 // all reads of this block's rows done before writes
    if (valid) out[(size_t)row * FO + c] = acc;
}

extern "C" void kernel_launch(void* const* d_in, const int* in_sizes, int n_in,
                              void* d_out, int out_size, void* d_ws, size_t ws_size,
                              hipStream_t stream) {
    const float* x  = (const float*)d_in[0];
    const int*   ei = (const int*)d_in[1];       // harness passes integers as int32
    const float* W1 = (const float*)d_in[2];
    const float* b1 = (const float*)d_in[3];
    const float* W2 = (const float*)d_in[4];
    const float* b2 = (const float*)d_in[5];
    float* out = (float*)d_out;

    int N = in_sizes[0] / FI;     // 50000
    int E = in_sizes[1] / 2;      // 1600000
    const int* src = ei;          // edge_index[0]
    const int* dst = ei + E;      // edge_index[1]

    float* dinv = (float*)d_ws;   // N floats = 200 KB of workspace, nothing else

    // degrees -> dinv
    zero_kernel<<<(N + 255) / 256, 256, 0, stream>>>(dinv, N);
    deg_kernel<<<(E + 255) / 256, 256, 0, stream>>>(dst, dinv, E);
    dinv_kernel<<<(N + 255) / 256, 256, 0, stream>>>(dinv, N);

    // layer 1: h1 -> upper halves; zero lower halves; aggregate; relu-fuse (re-zeroes lower)
    mm1_kernel<<<(N + 3) / 4, 256, 0, stream>>>(x, W1, out, N);
    zero_agg_kernel<<<((N * FH) + 255) / 256, 256, 0, stream>>>(out, N);
    scatter_kernel<<<(E + 3) / 4, 256, 0, stream>>>(src, dst, dinv, out, E);
    fuse_relu_kernel<<<((N * FH) + 255) / 256, 256, 0, stream>>>(out, dinv, b1, N);

    // layer 2: aggregate hidden; final matmul in place
    scatter_kernel<<<(E + 3) / 4, 256, 0, stream>>>(src, dst, dinv, out, E);
    mm2_kernel<<<(N + 1) / 2, 256, 0, stream>>>(dinv, W2, b2, out, N);
}

// Round 5
// 763.351 us; speedup vs baseline: 1.5315x; 1.5315x over previous
//
#include <hip/hip_runtime.h>

#define FI 256
#define FH 64
#define FO 128

// ---------------- common small kernels ----------------

__global__ void zero_f32(float* __restrict__ p, int n) {
    int i = blockIdx.x * 256 + threadIdx.x;
    if (i < n) p[i] = 0.f;
}

__global__ void zero_i32(int* __restrict__ p, int n) {
    int i = blockIdx.x * 256 + threadIdx.x;
    if (i < n) p[i] = 0;
}

// degree count (int)
__global__ void deg_cnt_kernel(const int* __restrict__ dst, int* __restrict__ cnt, int E) {
    int e = blockIdx.x * 256 + threadIdx.x;
    if (e < E) atomicAdd(&cnt[dst[e]], 1);
}

// dinv[i] = rsqrt(cnt[i] + 1)
__global__ void dinv_kernel(const int* __restrict__ cnt, float* __restrict__ dinv, int N) {
    int i = blockIdx.x * 256 + threadIdx.x;
    if (i < N) dinv[i] = rsqrtf((float)cnt[i] + 1.0f);
}

// ---------------- CSR build: scan + bucket scatter ----------------

// per-block (1024 elems) exclusive scan; block total -> blksum
__global__ void scan_block_kernel(const int* __restrict__ cnt, int* __restrict__ row_start,
                                  int* __restrict__ blksum, int N) {
    __shared__ int sh[256];
    int base = blockIdx.x * 1024 + threadIdx.x * 4;
    int v0 = 0, v1 = 0, v2 = 0, v3 = 0;
    if (base + 0 < N) v0 = cnt[base + 0];
    if (base + 1 < N) v1 = cnt[base + 1];
    if (base + 2 < N) v2 = cnt[base + 2];
    if (base + 3 < N) v3 = cnt[base + 3];
    sh[threadIdx.x] = v0 + v1 + v2 + v3;
    __syncthreads();
    // Hillis-Steele inclusive scan over 256
    for (int off = 1; off < 256; off <<= 1) {
        int t = (threadIdx.x >= off) ? sh[threadIdx.x - off] : 0;
        __syncthreads();
        sh[threadIdx.x] += t;
        __syncthreads();
    }
    int run = (threadIdx.x > 0) ? sh[threadIdx.x - 1] : 0;
    if (base + 0 < N) row_start[base + 0] = run; run += v0;
    if (base + 1 < N) row_start[base + 1] = run; run += v1;
    if (base + 2 < N) row_start[base + 2] = run; run += v2;
    if (base + 3 < N) row_start[base + 3] = run;
    if (threadIdx.x == 255) blksum[blockIdx.x] = sh[255];
}

// scan the (few dozen) block sums; tiny, single thread
__global__ void scan_top_kernel(int* __restrict__ blksum, int nb) {
    if (threadIdx.x == 0 && blockIdx.x == 0) {
        int acc = 0;
        for (int b = 0; b < nb; ++b) { int v = blksum[b]; blksum[b] = acc; acc += v; }
    }
}

// add block offsets; duplicate into pos (running cursors for bucket scatter)
__global__ void scan_add_kernel(int* __restrict__ row_start, int* __restrict__ pos,
                                const int* __restrict__ blksum, int N) {
    int i = blockIdx.x * 256 + threadIdx.x;
    if (i < N) {
        int v = row_start[i] + blksum[i >> 10];
        row_start[i] = v;
        pos[i] = v;
    }
}

// bucket-scatter edges by dst; precompute edge weight dinv[s]*dinv[d]
__global__ void edge_sort_kernel(const int* __restrict__ src, const int* __restrict__ dst,
                                 const float* __restrict__ dinv, int* __restrict__ pos,
                                 int* __restrict__ ssrc, float* __restrict__ sw, int E) {
    int e = blockIdx.x * 256 + threadIdx.x;
    if (e >= E) return;
    int s = src[e], d = dst[e];
    int p = atomicAdd(&pos[d], 1);
    ssrc[p] = s;
    sw[p]   = dinv[s] * dinv[d];
}

// ---------------- gather-side aggregation (no atomics) ----------------
// one wave per dst node; lane = feature; reads upper halves, writes own lower half
__global__ void gather_agg_kernel(const int* __restrict__ ssrc, const float* __restrict__ sw,
                                  const int* __restrict__ row_start, const int* __restrict__ cnt,
                                  float* __restrict__ out, int N) {
    int node = blockIdx.x * 4 + (threadIdx.x >> 6);
    if (node >= N) return;
    int lane = threadIdx.x & 63;
    int beg = row_start[node];
    int n   = cnt[node];
    float acc = 0.f;
    int i = 0;
    for (; i + 1 < n; i += 2) {
        int   s0 = ssrc[beg + i],   s1 = ssrc[beg + i + 1];
        float w0 = sw[beg + i],     w1 = sw[beg + i + 1];
        float h0 = out[(size_t)s0 * FO + FH + lane];
        float h1 = out[(size_t)s1 * FO + FH + lane];
        acc = fmaf(h0, w0, acc);
        acc = fmaf(h1, w1, acc);
    }
    if (i < n) {
        int s = ssrc[beg + i];
        acc = fmaf(out[(size_t)s * FO + FH + lane], sw[beg + i], acc);
    }
    out[(size_t)node * FO + lane] = acc;   // overwrite lower half (no pre-zero needed)
}

// ---------------- fallback path pieces (atomic scatter; used only if ws too small) ----------------

__global__ void zero_agg_kernel(float* __restrict__ out, int N) {
    int i = blockIdx.x * 256 + threadIdx.x;
    if (i >= N * FH) return;
    out[(size_t)(i >> 6) * FO + (i & 63)] = 0.f;
}

__global__ void scatter_kernel(const int* __restrict__ src, const int* __restrict__ dst,
                               const float* __restrict__ dinv, float* __restrict__ out, int E) {
    int e = blockIdx.x * 4 + (threadIdx.x >> 6);
    if (e >= E) return;
    int lane = threadIdx.x & 63;
    int s = src[e];
    int d = dst[e];
    float wgt = dinv[s] * dinv[d];
    float v = out[(size_t)s * FO + FH + lane] * wgt;
    atomicAdd(&out[(size_t)d * FO + lane], v);
}

// ---------------- dense kernels ----------------

// h1 = x @ W1 -> upper half of out rows; one wave per row, lane = out col
__global__ void mm1_kernel(const float* __restrict__ x, const float* __restrict__ W1,
                           float* __restrict__ out, int N) {
    __shared__ float Wl[128 * FH];   // 32 KB k-chunk of W1
    int lane = threadIdx.x & 63;
    int w    = threadIdx.x >> 6;
    int row  = blockIdx.x * 4 + w;
    float acc = 0.f;
    for (int half = 0; half < 2; ++half) {
        __syncthreads();
        for (int t = threadIdx.x; t < 128 * FH; t += 256)
            Wl[t] = W1[half * 128 * FH + t];
        __syncthreads();
        if (row < N) {
            const float* xr = x + (size_t)row * FI + half * 128;
            #pragma unroll 8
            for (int k = 0; k < 128; ++k)
                acc = fmaf(xr[k], Wl[k * FH + lane], acc);
        }
    }
    if (row < N) out[(size_t)row * FO + FH + lane] = acc;
}

// upper = relu(lower + upper*dinv^2 + b1)
__global__ void fuse_relu_kernel(float* __restrict__ out, const float* __restrict__ dinv,
                                 const float* __restrict__ b1, int N) {
    int i = blockIdx.x * 256 + threadIdx.x;
    if (i >= N * FH) return;
    int row = i >> 6;
    int c   = i & 63;
    size_t base = (size_t)row * FO;
    float s = dinv[row];
    float v = out[base + c] + out[base + FH + c] * s * s + b1[c];
    out[base + FH + c] = fmaxf(v, 0.f);
}

// out_row = (lower + upper*dinv^2) @ W2 + b2 ; in-place
__global__ void mm2_kernel(const float* __restrict__ dinv, const float* __restrict__ W2,
                           const float* __restrict__ b2, float* __restrict__ out, int N) {
    __shared__ float Wl[FH * FO];   // 32 KB
    for (int t = threadIdx.x; t < FH * FO; t += 256) Wl[t] = W2[t];
    __syncthreads();
    int c   = threadIdx.x & 127;
    int row = blockIdx.x * 2 + (threadIdx.x >> 7);
    bool valid = row < N;
    float acc = 0.f;
    if (valid) {
        float s = dinv[row]; s = s * s;
        const float* a = out + (size_t)row * FO;
        const float* h = a + FH;
        acc = b2[c];
        #pragma unroll 8
        for (int j = 0; j < FH; ++j)
            acc = fmaf(a[j] + h[j] * s, Wl[j * FO + c], acc);
    }
    __syncthreads();
    if (valid) out[(size_t)row * FO + c] = acc;
}

extern "C" void kernel_launch(void* const* d_in, const int* in_sizes, int n_in,
                              void* d_out, int out_size, void* d_ws, size_t ws_size,
                              hipStream_t stream) {
    const float* x  = (const float*)d_in[0];
    const int*   ei = (const int*)d_in[1];       // int32 indices
    const float* W1 = (const float*)d_in[2];
    const float* b1 = (const float*)d_in[3];
    const float* W2 = (const float*)d_in[4];
    const float* b2 = (const float*)d_in[5];
    float* out = (float*)d_out;

    int N = in_sizes[0] / FI;     // 50000
    int E = in_sizes[1] / 2;      // 1600000
    const int* src = ei;
    const int* dst = ei + E;

    // workspace layout
    char* w = (char*)d_ws;
    float* dinv      = (float*)w;            w += (size_t)N * 4;
    int*   cnt       = (int*)w;              w += (size_t)N * 4;
    int*   row_start = (int*)w;              w += (size_t)N * 4;
    int*   pos       = (int*)w;              w += (size_t)N * 4;
    int*   blksum    = (int*)w;              w += 256 * 4;
    int*   ssrc      = (int*)w;              w += (size_t)E * 4;
    float* sw        = (float*)w;            w += (size_t)E * 4;
    size_t need = (size_t)(w - (char*)d_ws);

    int nb = (N + 1023) / 1024;

    // degrees (int) -> dinv
    zero_i32<<<(N + 255) / 256, 256, 0, stream>>>(cnt, N);
    deg_cnt_kernel<<<(E + 255) / 256, 256, 0, stream>>>(dst, cnt, E);
    dinv_kernel<<<(N + 255) / 256, 256, 0, stream>>>(cnt, dinv, N);

    if (ws_size >= need) {
        // CSR build (once; reused by both layers)
        scan_block_kernel<<<nb, 256, 0, stream>>>(cnt, row_start, blksum, N);
        scan_top_kernel<<<1, 64, 0, stream>>>(blksum, nb);
        scan_add_kernel<<<(N + 255) / 256, 256, 0, stream>>>(row_start, pos, blksum, N);
        edge_sort_kernel<<<(E + 255) / 256, 256, 0, stream>>>(src, dst, dinv, pos, ssrc, sw, E);

        // layer 1
        mm1_kernel<<<(N + 3) / 4, 256, 0, stream>>>(x, W1, out, N);
        gather_agg_kernel<<<(N + 3) / 4, 256, 0, stream>>>(ssrc, sw, row_start, cnt, out, N);
        fuse_relu_kernel<<<((N * FH) + 255) / 256, 256, 0, stream>>>(out, dinv, b1, N);

        // layer 2
        gather_agg_kernel<<<(N + 3) / 4, 256, 0, stream>>>(ssrc, sw, row_start, cnt, out, N);
        mm2_kernel<<<(N + 1) / 2, 256, 0, stream>>>(dinv, W2, b2, out, N);
    } else {
        // fallback: proven atomic-scatter path (round-4 behavior)
        mm1_kernel<<<(N + 3) / 4, 256, 0, stream>>>(x, W1, out, N);
        zero_agg_kernel<<<((N * FH) + 255) / 256, 256, 0, stream>>>(out, N);
        scatter_kernel<<<(E + 3) / 4, 256, 0, stream>>>(src, dst, dinv, out, E);
        fuse_relu_kernel<<<((N * FH) + 255) / 256, 256, 0, stream>>>(out, dinv, b1, N);
        zero_agg_kernel<<<((N * FH) + 255) / 256, 256, 0, stream>>>(out, N);
        scatter_kernel<<<(E + 3) / 4, 256, 0, stream>>>(src, dst, dinv, out, E);
        mm2_kernel<<<(N + 1) / 2, 256, 0, stream>>>(dinv, W2, b2, out, N);
    }
}

// Round 6
// 521.223 us; speedup vs baseline: 2.2429x; 1.4645x over previous
//
#include <hip/hip_runtime.h>

#define FI 256
#define FH 64
#define FO 128

// ---------------- common small kernels ----------------

__global__ void zero_i32(int* __restrict__ p, int n) {
    int i = blockIdx.x * 256 + threadIdx.x;
    if (i < n) p[i] = 0;
}

__global__ void deg_cnt_kernel(const int* __restrict__ dst, int* __restrict__ cnt, int E) {
    int e = blockIdx.x * 256 + threadIdx.x;
    if (e < E) atomicAdd(&cnt[dst[e]], 1);
}

__global__ void dinv_kernel(const int* __restrict__ cnt, float* __restrict__ dinv, int N) {
    int i = blockIdx.x * 256 + threadIdx.x;
    if (i < N) dinv[i] = rsqrtf((float)cnt[i] + 1.0f);
}

// ---------------- CSR build: scan + bucket scatter ----------------

__global__ void scan_block_kernel(const int* __restrict__ cnt, int* __restrict__ row_start,
                                  int* __restrict__ blksum, int N) {
    __shared__ int sh[256];
    int base = blockIdx.x * 1024 + threadIdx.x * 4;
    int v0 = 0, v1 = 0, v2 = 0, v3 = 0;
    if (base + 0 < N) v0 = cnt[base + 0];
    if (base + 1 < N) v1 = cnt[base + 1];
    if (base + 2 < N) v2 = cnt[base + 2];
    if (base + 3 < N) v3 = cnt[base + 3];
    sh[threadIdx.x] = v0 + v1 + v2 + v3;
    __syncthreads();
    for (int off = 1; off < 256; off <<= 1) {
        int t = (threadIdx.x >= off) ? sh[threadIdx.x - off] : 0;
        __syncthreads();
        sh[threadIdx.x] += t;
        __syncthreads();
    }
    int run = (threadIdx.x > 0) ? sh[threadIdx.x - 1] : 0;
    if (base + 0 < N) row_start[base + 0] = run; run += v0;
    if (base + 1 < N) row_start[base + 1] = run; run += v1;
    if (base + 2 < N) row_start[base + 2] = run; run += v2;
    if (base + 3 < N) row_start[base + 3] = run;
    if (threadIdx.x == 255) blksum[blockIdx.x] = sh[255];
}

__global__ void scan_top_kernel(int* __restrict__ blksum, int nb) {
    if (threadIdx.x == 0 && blockIdx.x == 0) {
        int acc = 0;
        for (int b = 0; b < nb; ++b) { int v = blksum[b]; blksum[b] = acc; acc += v; }
    }
}

__global__ void scan_add_kernel(int* __restrict__ row_start, int* __restrict__ pos,
                                const int* __restrict__ blksum, int N) {
    int i = blockIdx.x * 256 + threadIdx.x;
    if (i < N) {
        int v = row_start[i] + blksum[i >> 10];
        row_start[i] = v;
        pos[i] = v;
    }
}

__global__ void edge_sort_kernel(const int* __restrict__ src, const int* __restrict__ dst,
                                 const float* __restrict__ dinv, int* __restrict__ pos,
                                 int* __restrict__ ssrc, float* __restrict__ sw, int E) {
    int e = blockIdx.x * 256 + threadIdx.x;
    if (e >= E) return;
    int s = src[e], d = dst[e];
    int p = atomicAdd(&pos[d], 1);
    ssrc[p] = s;
    sw[p]   = dinv[s] * dinv[d];
}

// ---------------- gather-side aggregation (no atomics) ----------------

__global__ void gather_agg_kernel(const int* __restrict__ ssrc, const float* __restrict__ sw,
                                  const int* __restrict__ row_start, const int* __restrict__ cnt,
                                  float* __restrict__ out, int N) {
    int node = blockIdx.x * 4 + (threadIdx.x >> 6);
    if (node >= N) return;
    int lane = threadIdx.x & 63;
    int beg = row_start[node];
    int n   = cnt[node];
    float acc = 0.f;
    int i = 0;
    for (; i + 1 < n; i += 2) {
        int   s0 = ssrc[beg + i],   s1 = ssrc[beg + i + 1];
        float w0 = sw[beg + i],     w1 = sw[beg + i + 1];
        float h0 = out[(size_t)s0 * FO + FH + lane];
        float h1 = out[(size_t)s1 * FO + FH + lane];
        acc = fmaf(h0, w0, acc);
        acc = fmaf(h1, w1, acc);
    }
    if (i < n) {
        int s = ssrc[beg + i];
        acc = fmaf(out[(size_t)s * FO + FH + lane], sw[beg + i], acc);
    }
    out[(size_t)node * FO + lane] = acc;
}

// ---------------- fallback (atomic scatter) pieces ----------------

__global__ void zero_agg_kernel(float* __restrict__ out, int N) {
    int i = blockIdx.x * 256 + threadIdx.x;
    if (i >= N * FH) return;
    out[(size_t)(i >> 6) * FO + (i & 63)] = 0.f;
}

__global__ void scatter_kernel(const int* __restrict__ src, const int* __restrict__ dst,
                               const float* __restrict__ dinv, float* __restrict__ out, int E) {
    int e = blockIdx.x * 4 + (threadIdx.x >> 6);
    if (e >= E) return;
    int lane = threadIdx.x & 63;
    int s = src[e];
    int d = dst[e];
    float wgt = dinv[s] * dinv[d];
    float v = out[(size_t)s * FO + FH + lane] * wgt;
    atomicAdd(&out[(size_t)d * FO + lane], v);
}

// ---------------- dense kernels: register-tiled SGEMM ----------------

// mm1: h1 = x @ W1 -> out[row][64..127]. Tile 128 rows x 64 cols, 256 thr, 4x8/thread.
__global__ __launch_bounds__(256) void mm1_tiled(const float* __restrict__ x,
                                                 const float* __restrict__ W1,
                                                 float* __restrict__ out, int N) {
    __shared__ float xs[32][128];   // transposed x chunk: xs[k][r]   (16 KB)
    __shared__ float ws[32][64];    // W1 chunk: ws[k][c]             (8 KB)
    int tid = threadIdx.x;
    int R0  = blockIdx.x * 128;
    int ty  = tid >> 3;             // 0..31 -> rows ty*4..+3
    int tx  = tid & 7;              // 0..7  -> cols tx*4..+3 and 32+tx*4..+3
    float acc[4][8];
    #pragma unroll
    for (int i = 0; i < 4; ++i)
        #pragma unroll
        for (int j = 0; j < 8; ++j) acc[i][j] = 0.f;

    int sr = tid >> 1;              // staging row 0..127
    int sk = (tid & 1) * 16;        // staging k-offset 0 or 16
    bool row_ok = (R0 + sr) < N;
    const float* xrow = x + (size_t)(R0 + sr) * FI;

    for (int k0 = 0; k0 < FI; k0 += 32) {
        __syncthreads();
        // stage x transposed: each thread 4 float4 = 16 k-values of its row
        #pragma unroll
        for (int q = 0; q < 4; ++q) {
            float4 v = row_ok ? *(const float4*)&xrow[k0 + sk + q * 4]
                              : make_float4(0.f, 0.f, 0.f, 0.f);
            xs[sk + q * 4 + 0][sr] = v.x;
            xs[sk + q * 4 + 1][sr] = v.y;
            xs[sk + q * 4 + 2][sr] = v.z;
            xs[sk + q * 4 + 3][sr] = v.w;
        }
        // stage W1 chunk: 512 float4 / 256 threads = 2 each, flat copy
        {
            int f = tid * 2;
            *(float4*)&ws[0][0 + f * 4]     = *(const float4*)&W1[(size_t)k0 * 64 + f * 4];
            *(float4*)&ws[0][0 + f * 4 + 4] = *(const float4*)&W1[(size_t)k0 * 64 + f * 4 + 4];
        }
        __syncthreads();
        #pragma unroll 4
        for (int k = 0; k < 32; ++k) {
            float4 a  = *(const float4*)&xs[k][ty * 4];
            float4 bl = *(const float4*)&ws[k][tx * 4];
            float4 bh = *(const float4*)&ws[k][32 + tx * 4];
            float av[4] = {a.x, a.y, a.z, a.w};
            float bv[8] = {bl.x, bl.y, bl.z, bl.w, bh.x, bh.y, bh.z, bh.w};
            #pragma unroll
            for (int i = 0; i < 4; ++i)
                #pragma unroll
                for (int j = 0; j < 8; ++j)
                    acc[i][j] = fmaf(av[i], bv[j], acc[i][j]);
        }
    }
    // writeback: h1 -> upper half (cols 64 + c)
    #pragma unroll
    for (int i = 0; i < 4; ++i) {
        int row = R0 + ty * 4 + i;
        if (row < N) {
            float* o = out + (size_t)row * FO + FH;
            *(float4*)&o[tx * 4]      = make_float4(acc[i][0], acc[i][1], acc[i][2], acc[i][3]);
            *(float4*)&o[32 + tx * 4] = make_float4(acc[i][4], acc[i][5], acc[i][6], acc[i][7]);
        }
    }
}

// mm2: out_row = (lower + upper*dinv^2) @ W2 + b2, in place.
// Tile 64 rows x 128 cols, 256 thr, 4x8/thread, K=64 single stage.
__global__ __launch_bounds__(256) void mm2_tiled(const float* __restrict__ dinv,
                                                 const float* __restrict__ W2,
                                                 const float* __restrict__ b2,
                                                 float* __restrict__ out, int N) {
    __shared__ float xs[64][68];    // combined input transposed: xs[j][r] (17.4 KB, pad 68)
    __shared__ float ws[64][128];   // W2: ws[j][c] (32 KB)
    int tid = threadIdx.x;
    int R0  = blockIdx.x * 64;
    int ty  = tid >> 4;             // 0..15 -> rows ty*4..+3
    int tx  = tid & 15;             // 0..15 -> cols tx*4..+3 and 64+tx*4..+3

    // stage combined input: thread handles row sr = tid>>2, quads l4 + 4q
    {
        int sr = tid >> 2;
        int l4 = tid & 3;
        int grow = R0 + sr;
        bool ok = grow < N;
        float s = ok ? dinv[grow] : 0.f;
        s = s * s;
        const float* orow = out + (size_t)grow * FO;
        #pragma unroll
        for (int q = 0; q < 4; ++q) {
            int j0 = (l4 + 4 * q) * 4;
            float4 a = ok ? *(const float4*)&orow[j0]      : make_float4(0.f, 0.f, 0.f, 0.f);
            float4 h = ok ? *(const float4*)&orow[FH + j0] : make_float4(0.f, 0.f, 0.f, 0.f);
            xs[j0 + 0][sr] = fmaf(h.x, s, a.x);
            xs[j0 + 1][sr] = fmaf(h.y, s, a.y);
            xs[j0 + 2][sr] = fmaf(h.z, s, a.z);
            xs[j0 + 3][sr] = fmaf(h.w, s, a.w);
        }
    }
    // stage W2: 2048 float4 / 256 = 8 each, flat copy
    #pragma unroll
    for (int q = 0; q < 8; ++q) {
        int f = tid + q * 256;
        *(float4*)&ws[f >> 5][(f & 31) * 4] = *(const float4*)&W2[(size_t)f * 4];
    }
    __syncthreads();

    float acc[4][8];
    #pragma unroll
    for (int i = 0; i < 4; ++i)
        #pragma unroll
        for (int j = 0; j < 8; ++j) acc[i][j] = 0.f;

    #pragma unroll 4
    for (int k = 0; k < FH; ++k) {
        float4 a  = *(const float4*)&xs[k][ty * 4];
        float4 bl = *(const float4*)&ws[k][tx * 4];
        float4 bh = *(const float4*)&ws[k][64 + tx * 4];
        float av[4] = {a.x, a.y, a.z, a.w};
        float bv[8] = {bl.x, bl.y, bl.z, bl.w, bh.x, bh.y, bh.z, bh.w};
        #pragma unroll
        for (int i = 0; i < 4; ++i)
            #pragma unroll
            for (int j = 0; j < 8; ++j)
                acc[i][j] = fmaf(av[i], bv[j], acc[i][j]);
    }

    float4 b2l = *(const float4*)&b2[tx * 4];
    float4 b2h = *(const float4*)&b2[64 + tx * 4];
    #pragma unroll
    for (int i = 0; i < 4; ++i) {
        int row = R0 + ty * 4 + i;
        if (row < N) {
            float* o = out + (size_t)row * FO;
            *(float4*)&o[tx * 4] = make_float4(acc[i][0] + b2l.x, acc[i][1] + b2l.y,
                                               acc[i][2] + b2l.z, acc[i][3] + b2l.w);
            *(float4*)&o[64 + tx * 4] = make_float4(acc[i][4] + b2h.x, acc[i][5] + b2h.y,
                                                    acc[i][6] + b2h.z, acc[i][7] + b2h.w);
        }
    }
}

// upper = relu(lower + upper*dinv^2 + b1)
__global__ void fuse_relu_kernel(float* __restrict__ out, const float* __restrict__ dinv,
                                 const float* __restrict__ b1, int N) {
    int i = blockIdx.x * 256 + threadIdx.x;
    if (i >= N * FH) return;
    int row = i >> 6;
    int c   = i & 63;
    size_t base = (size_t)row * FO;
    float s = dinv[row];
    float v = out[base + c] + out[base + FH + c] * s * s + b1[c];
    out[base + FH + c] = fmaxf(v, 0.f);
}

extern "C" void kernel_launch(void* const* d_in, const int* in_sizes, int n_in,
                              void* d_out, int out_size, void* d_ws, size_t ws_size,
                              hipStream_t stream) {
    const float* x  = (const float*)d_in[0];
    const int*   ei = (const int*)d_in[1];
    const float* W1 = (const float*)d_in[2];
    const float* b1 = (const float*)d_in[3];
    const float* W2 = (const float*)d_in[4];
    const float* b2 = (const float*)d_in[5];
    float* out = (float*)d_out;

    int N = in_sizes[0] / FI;     // 50000
    int E = in_sizes[1] / 2;      // 1600000
    const int* src = ei;
    const int* dst = ei + E;

    char* w = (char*)d_ws;
    float* dinv      = (float*)w;            w += (size_t)N * 4;
    int*   cnt       = (int*)w;              w += (size_t)N * 4;
    int*   row_start = (int*)w;              w += (size_t)N * 4;
    int*   pos       = (int*)w;              w += (size_t)N * 4;
    int*   blksum    = (int*)w;              w += 256 * 4;
    int*   ssrc      = (int*)w;              w += (size_t)E * 4;
    float* sw        = (float*)w;            w += (size_t)E * 4;
    size_t need = (size_t)(w - (char*)d_ws);

    int nb = (N + 1023) / 1024;

    zero_i32<<<(N + 255) / 256, 256, 0, stream>>>(cnt, N);
    deg_cnt_kernel<<<(E + 255) / 256, 256, 0, stream>>>(dst, cnt, E);
    dinv_kernel<<<(N + 255) / 256, 256, 0, stream>>>(cnt, dinv, N);

    if (ws_size >= need) {
        scan_block_kernel<<<nb, 256, 0, stream>>>(cnt, row_start, blksum, N);
        scan_top_kernel<<<1, 64, 0, stream>>>(blksum, nb);
        scan_add_kernel<<<(N + 255) / 256, 256, 0, stream>>>(row_start, pos, blksum, N);
        edge_sort_kernel<<<(E + 255) / 256, 256, 0, stream>>>(src, dst, dinv, pos, ssrc, sw, E);

        mm1_tiled<<<(N + 127) / 128, 256, 0, stream>>>(x, W1, out, N);
        gather_agg_kernel<<<(N + 3) / 4, 256, 0, stream>>>(ssrc, sw, row_start, cnt, out, N);
        fuse_relu_kernel<<<((N * FH) + 255) / 256, 256, 0, stream>>>(out, dinv, b1, N);

        gather_agg_kernel<<<(N + 3) / 4, 256, 0, stream>>>(ssrc, sw, row_start, cnt, out, N);
        mm2_tiled<<<(N + 63) / 64, 256, 0, stream>>>(dinv, W2, b2, out, N);
    } else {
        // fallback: atomic scatter path
        mm1_tiled<<<(N + 127) / 128, 256, 0, stream>>>(x, W1, out, N);
        zero_agg_kernel<<<((N * FH) + 255) / 256, 256, 0, stream>>>(out, N);
        scatter_kernel<<<(E + 3) / 4, 256, 0, stream>>>(src, dst, dinv, out, E);
        fuse_relu_kernel<<<((N * FH) + 255) / 256, 256, 0, stream>>>(out, dinv, b1, N);
        zero_agg_kernel<<<((N * FH) + 255) / 256, 256, 0, stream>>>(out, N);
        scatter_kernel<<<(E + 3) / 4, 256, 0, stream>>>(src, dst, dinv, out, E);
        mm2_tiled<<<(N + 63) / 64, 256, 0, stream>>>(dinv, W2, b2, out, N);
    }
}

// Round 7
// 424.769 us; speedup vs baseline: 2.7522x; 1.2271x over previous
//
#include <hip/hip_runtime.h>

#define FI 256
#define FH 64
#define FO 128

// ---------------- common small kernels ----------------

__global__ void zero_i32(int* __restrict__ p, int n) {
    int i = blockIdx.x * 256 + threadIdx.x;
    if (i < n) p[i] = 0;
}

__global__ void deg_cnt_kernel(const int* __restrict__ dst, int* __restrict__ cnt, int E) {
    int e = blockIdx.x * 256 + threadIdx.x;
    if (e < E) atomicAdd(&cnt[dst[e]], 1);
}

__global__ void dinv_kernel(const int* __restrict__ cnt, float* __restrict__ dinv, int N) {
    int i = blockIdx.x * 256 + threadIdx.x;
    if (i < N) dinv[i] = rsqrtf((float)cnt[i] + 1.0f);
}

// ---------------- CSR build: scan + bucket scatter ----------------

__global__ void scan_block_kernel(const int* __restrict__ cnt, int* __restrict__ row_start,
                                  int* __restrict__ blksum, int N) {
    __shared__ int sh[256];
    int base = blockIdx.x * 1024 + threadIdx.x * 4;
    int v0 = 0, v1 = 0, v2 = 0, v3 = 0;
    if (base + 0 < N) v0 = cnt[base + 0];
    if (base + 1 < N) v1 = cnt[base + 1];
    if (base + 2 < N) v2 = cnt[base + 2];
    if (base + 3 < N) v3 = cnt[base + 3];
    sh[threadIdx.x] = v0 + v1 + v2 + v3;
    __syncthreads();
    for (int off = 1; off < 256; off <<= 1) {
        int t = (threadIdx.x >= off) ? sh[threadIdx.x - off] : 0;
        __syncthreads();
        sh[threadIdx.x] += t;
        __syncthreads();
    }
    int run = (threadIdx.x > 0) ? sh[threadIdx.x - 1] : 0;
    if (base + 0 < N) row_start[base + 0] = run; run += v0;
    if (base + 1 < N) row_start[base + 1] = run; run += v1;
    if (base + 2 < N) row_start[base + 2] = run; run += v2;
    if (base + 3 < N) row_start[base + 3] = run;
    if (threadIdx.x == 255) blksum[blockIdx.x] = sh[255];
}

__global__ void scan_top_kernel(int* __restrict__ blksum, int nb) {
    if (threadIdx.x == 0 && blockIdx.x == 0) {
        int acc = 0;
        for (int b = 0; b < nb; ++b) { int v = blksum[b]; blksum[b] = acc; acc += v; }
    }
}

__global__ void scan_add_kernel(int* __restrict__ row_start, int* __restrict__ pos,
                                const int* __restrict__ blksum, int N) {
    int i = blockIdx.x * 256 + threadIdx.x;
    if (i < N) {
        int v = row_start[i] + blksum[i >> 10];
        row_start[i] = v;
        pos[i] = v;
    }
}

// bucket-scatter edges by dst; ONE 8-byte packed record (src, w) per edge
__global__ void edge_sort_kernel(const int* __restrict__ src, const int* __restrict__ dst,
                                 const float* __restrict__ dinv, int* __restrict__ pos,
                                 int2* __restrict__ rec, int E) {
    int e = blockIdx.x * 256 + threadIdx.x;
    if (e >= E) return;
    int s = src[e], d = dst[e];
    int p = atomicAdd(&pos[d], 1);
    int2 r;
    r.x = s;
    r.y = __float_as_int(dinv[s] * dinv[d]);
    rec[p] = r;                       // single aligned 8B scattered store
}

// ---------------- gather-side aggregation (no atomics), ping-pong halves ----------------

// layer 1: read h1 from UPPER halves; write relu(agg + h_own*s^2 + b1) to LOWER half
__global__ void gather_relu_kernel(const int2* __restrict__ rec, const int* __restrict__ row_start,
                                   const int* __restrict__ cnt, const float* __restrict__ dinv,
                                   const float* __restrict__ b1, float* __restrict__ out, int N) {
    int node = blockIdx.x * 4 + (threadIdx.x >> 6);
    if (node >= N) return;
    int lane = threadIdx.x & 63;
    int beg = row_start[node];
    int n   = cnt[node];
    float acc = 0.f;
    int i = 0;
    for (; i + 3 < n; i += 4) {
        int2 r0 = rec[beg + i], r1 = rec[beg + i + 1];
        int2 r2 = rec[beg + i + 2], r3 = rec[beg + i + 3];
        float h0 = out[(size_t)r0.x * FO + FH + lane];
        float h1 = out[(size_t)r1.x * FO + FH + lane];
        float h2 = out[(size_t)r2.x * FO + FH + lane];
        float h3 = out[(size_t)r3.x * FO + FH + lane];
        acc = fmaf(h0, __int_as_float(r0.y), acc);
        acc = fmaf(h1, __int_as_float(r1.y), acc);
        acc = fmaf(h2, __int_as_float(r2.y), acc);
        acc = fmaf(h3, __int_as_float(r3.y), acc);
    }
    for (; i < n; ++i) {
        int2 r = rec[beg + i];
        acc = fmaf(out[(size_t)r.x * FO + FH + lane], __int_as_float(r.y), acc);
    }
    float s = dinv[node];
    float v = acc + out[(size_t)node * FO + FH + lane] * s * s + b1[lane];
    out[(size_t)node * FO + lane] = fmaxf(v, 0.f);
}

// layer 2: read hrelu from LOWER halves; write (agg + h_own*s^2) to UPPER half
__global__ void gather_comb_kernel(const int2* __restrict__ rec, const int* __restrict__ row_start,
                                   const int* __restrict__ cnt, const float* __restrict__ dinv,
                                   float* __restrict__ out, int N) {
    int node = blockIdx.x * 4 + (threadIdx.x >> 6);
    if (node >= N) return;
    int lane = threadIdx.x & 63;
    int beg = row_start[node];
    int n   = cnt[node];
    float acc = 0.f;
    int i = 0;
    for (; i + 3 < n; i += 4) {
        int2 r0 = rec[beg + i], r1 = rec[beg + i + 1];
        int2 r2 = rec[beg + i + 2], r3 = rec[beg + i + 3];
        float h0 = out[(size_t)r0.x * FO + lane];
        float h1 = out[(size_t)r1.x * FO + lane];
        float h2 = out[(size_t)r2.x * FO + lane];
        float h3 = out[(size_t)r3.x * FO + lane];
        acc = fmaf(h0, __int_as_float(r0.y), acc);
        acc = fmaf(h1, __int_as_float(r1.y), acc);
        acc = fmaf(h2, __int_as_float(r2.y), acc);
        acc = fmaf(h3, __int_as_float(r3.y), acc);
    }
    for (; i < n; ++i) {
        int2 r = rec[beg + i];
        acc = fmaf(out[(size_t)r.x * FO + lane], __int_as_float(r.y), acc);
    }
    float s = dinv[node];
    out[(size_t)node * FO + FH + lane] = acc + out[(size_t)node * FO + lane] * s * s;
}

// ---------------- fallback (atomic scatter) pieces ----------------

__global__ void zero_half_kernel(float* __restrict__ out, int half, int N) {
    int i = blockIdx.x * 256 + threadIdx.x;
    if (i >= N * FH) return;
    out[(size_t)(i >> 6) * FO + half + (i & 63)] = 0.f;
}

__global__ void scatter_half_kernel(const int* __restrict__ src, const int* __restrict__ dst,
                                    const float* __restrict__ dinv, float* __restrict__ out,
                                    int rh, int wh, int E) {
    int e = blockIdx.x * 4 + (threadIdx.x >> 6);
    if (e >= E) return;
    int lane = threadIdx.x & 63;
    int s = src[e];
    int d = dst[e];
    float wgt = dinv[s] * dinv[d];
    float v = out[(size_t)s * FO + rh + lane] * wgt;
    atomicAdd(&out[(size_t)d * FO + wh + lane], v);
}

// lower = relu(lower + upper*s^2 + b1)
__global__ void finish1_kernel(float* __restrict__ out, const float* __restrict__ dinv,
                               const float* __restrict__ b1, int N) {
    int i = blockIdx.x * 256 + threadIdx.x;
    if (i >= N * FH) return;
    int row = i >> 6;
    int c   = i & 63;
    size_t base = (size_t)row * FO;
    float s = dinv[row];
    out[base + c] = fmaxf(out[base + c] + out[base + FH + c] * s * s + b1[c], 0.f);
}

// upper = upper + lower*s^2
__global__ void finish2_kernel(float* __restrict__ out, const float* __restrict__ dinv, int N) {
    int i = blockIdx.x * 256 + threadIdx.x;
    if (i >= N * FH) return;
    int row = i >> 6;
    int c   = i & 63;
    size_t base = (size_t)row * FO;
    float s = dinv[row];
    out[base + FH + c] += out[base + c] * s * s;
}

// ---------------- dense kernels: register-tiled SGEMM ----------------

// mm1: h1 = x @ W1 -> out[row][64..127]. Tile 128 rows x 64 cols, 256 thr, 4x8/thread.
__global__ __launch_bounds__(256) void mm1_tiled(const float* __restrict__ x,
                                                 const float* __restrict__ W1,
                                                 float* __restrict__ out, int N) {
    __shared__ float xs[32][128];   // transposed x chunk: xs[k][r]   (16 KB)
    __shared__ float ws[32][64];    // W1 chunk: ws[k][c]             (8 KB)
    int tid = threadIdx.x;
    int R0  = blockIdx.x * 128;
    int ty  = tid >> 3;
    int tx  = tid & 7;
    float acc[4][8];
    #pragma unroll
    for (int i = 0; i < 4; ++i)
        #pragma unroll
        for (int j = 0; j < 8; ++j) acc[i][j] = 0.f;

    int sr = tid >> 1;
    int sk = (tid & 1) * 16;
    bool row_ok = (R0 + sr) < N;
    const float* xrow = x + (size_t)(R0 + sr) * FI;

    for (int k0 = 0; k0 < FI; k0 += 32) {
        __syncthreads();
        #pragma unroll
        for (int q = 0; q < 4; ++q) {
            float4 v = row_ok ? *(const float4*)&xrow[k0 + sk + q * 4]
                              : make_float4(0.f, 0.f, 0.f, 0.f);
            xs[sk + q * 4 + 0][sr] = v.x;
            xs[sk + q * 4 + 1][sr] = v.y;
            xs[sk + q * 4 + 2][sr] = v.z;
            xs[sk + q * 4 + 3][sr] = v.w;
        }
        {
            int f = tid * 2;
            *(float4*)&ws[0][0 + f * 4]     = *(const float4*)&W1[(size_t)k0 * 64 + f * 4];
            *(float4*)&ws[0][0 + f * 4 + 4] = *(const float4*)&W1[(size_t)k0 * 64 + f * 4 + 4];
        }
        __syncthreads();
        #pragma unroll 4
        for (int k = 0; k < 32; ++k) {
            float4 a  = *(const float4*)&xs[k][ty * 4];
            float4 bl = *(const float4*)&ws[k][tx * 4];
            float4 bh = *(const float4*)&ws[k][32 + tx * 4];
            float av[4] = {a.x, a.y, a.z, a.w};
            float bv[8] = {bl.x, bl.y, bl.z, bl.w, bh.x, bh.y, bh.z, bh.w};
            #pragma unroll
            for (int i = 0; i < 4; ++i)
                #pragma unroll
                for (int j = 0; j < 8; ++j)
                    acc[i][j] = fmaf(av[i], bv[j], acc[i][j]);
        }
    }
    #pragma unroll
    for (int i = 0; i < 4; ++i) {
        int row = R0 + ty * 4 + i;
        if (row < N) {
            float* o = out + (size_t)row * FO + FH;
            *(float4*)&o[tx * 4]      = make_float4(acc[i][0], acc[i][1], acc[i][2], acc[i][3]);
            *(float4*)&o[32 + tx * 4] = make_float4(acc[i][4], acc[i][5], acc[i][6], acc[i][7]);
        }
    }
}

// mm2: out_row = upper_combined @ W2 + b2, in place (reads upper halves of own rows only).
__global__ __launch_bounds__(256) void mm2_tiled(const float* __restrict__ W2,
                                                 const float* __restrict__ b2,
                                                 float* __restrict__ out, int N) {
    __shared__ float xs[64][68];    // combined input transposed: xs[j][r]
    __shared__ float ws[64][128];   // W2
    int tid = threadIdx.x;
    int R0  = blockIdx.x * 64;
    int ty  = tid >> 4;
    int tx  = tid & 15;

    {
        int sr = tid >> 2;
        int l4 = tid & 3;
        int grow = R0 + sr;
        bool ok = grow < N;
        const float* orow = out + (size_t)grow * FO + FH;   // combined input in upper half
        #pragma unroll
        for (int q = 0; q < 4; ++q) {
            int j0 = (l4 + 4 * q) * 4;
            float4 a = ok ? *(const float4*)&orow[j0] : make_float4(0.f, 0.f, 0.f, 0.f);
            xs[j0 + 0][sr] = a.x;
            xs[j0 + 1][sr] = a.y;
            xs[j0 + 2][sr] = a.z;
            xs[j0 + 3][sr] = a.w;
        }
    }
    #pragma unroll
    for (int q = 0; q < 8; ++q) {
        int f = tid + q * 256;
        *(float4*)&ws[f >> 5][(f & 31) * 4] = *(const float4*)&W2[(size_t)f * 4];
    }
    __syncthreads();   // all reads of this block's rows done before any writes below

    float acc[4][8];
    #pragma unroll
    for (int i = 0; i < 4; ++i)
        #pragma unroll
        for (int j = 0; j < 8; ++j) acc[i][j] = 0.f;

    #pragma unroll 4
    for (int k = 0; k < FH; ++k) {
        float4 a  = *(const float4*)&xs[k][ty * 4];
        float4 bl = *(const float4*)&ws[k][tx * 4];
        float4 bh = *(const float4*)&ws[k][64 + tx * 4];
        float av[4] = {a.x, a.y, a.z, a.w};
        float bv[8] = {bl.x, bl.y, bl.z, bl.w, bh.x, bh.y, bh.z, bh.w};
        #pragma unroll
        for (int i = 0; i < 4; ++i)
            #pragma unroll
            for (int j = 0; j < 8; ++j)
                acc[i][j] = fmaf(av[i], bv[j], acc[i][j]);
    }

    float4 b2l = *(const float4*)&b2[tx * 4];
    float4 b2h = *(const float4*)&b2[64 + tx * 4];
    #pragma unroll
    for (int i = 0; i < 4; ++i) {
        int row = R0 + ty * 4 + i;
        if (row < N) {
            float* o = out + (size_t)row * FO;
            *(float4*)&o[tx * 4] = make_float4(acc[i][0] + b2l.x, acc[i][1] + b2l.y,
                                               acc[i][2] + b2l.z, acc[i][3] + b2l.w);
            *(float4*)&o[64 + tx * 4] = make_float4(acc[i][4] + b2h.x, acc[i][5] + b2h.y,
                                                    acc[i][6] + b2h.z, acc[i][7] + b2h.w);
        }
    }
}

extern "C" void kernel_launch(void* const* d_in, const int* in_sizes, int n_in,
                              void* d_out, int out_size, void* d_ws, size_t ws_size,
                              hipStream_t stream) {
    const float* x  = (const float*)d_in[0];
    const int*   ei = (const int*)d_in[1];
    const float* W1 = (const float*)d_in[2];
    const float* b1 = (const float*)d_in[3];
    const float* W2 = (const float*)d_in[4];
    const float* b2 = (const float*)d_in[5];
    float* out = (float*)d_out;

    int N = in_sizes[0] / FI;     // 50000
    int E = in_sizes[1] / 2;      // 1600000
    const int* src = ei;
    const int* dst = ei + E;

    char* w = (char*)d_ws;
    float* dinv      = (float*)w;            w += (size_t)N * 4;
    int*   cnt       = (int*)w;              w += (size_t)N * 4;
    int*   row_start = (int*)w;              w += (size_t)N * 4;
    int*   pos       = (int*)w;              w += (size_t)N * 4;
    int*   blksum    = (int*)w;              w += 256 * 4;
    int2*  rec       = (int2*)w;             w += (size_t)E * 8;   // 8B-aligned (offset 16N+1024)
    size_t need = (size_t)(w - (char*)d_ws);

    int nb = (N + 1023) / 1024;

    zero_i32<<<(N + 255) / 256, 256, 0, stream>>>(cnt, N);
    deg_cnt_kernel<<<(E + 255) / 256, 256, 0, stream>>>(dst, cnt, E);
    dinv_kernel<<<(N + 255) / 256, 256, 0, stream>>>(cnt, dinv, N);

    if (ws_size >= need) {
        scan_block_kernel<<<nb, 256, 0, stream>>>(cnt, row_start, blksum, N);
        scan_top_kernel<<<1, 64, 0, stream>>>(blksum, nb);
        scan_add_kernel<<<(N + 255) / 256, 256, 0, stream>>>(row_start, pos, blksum, N);
        edge_sort_kernel<<<(E + 255) / 256, 256, 0, stream>>>(src, dst, dinv, pos, rec, E);

        mm1_tiled<<<(N + 127) / 128, 256, 0, stream>>>(x, W1, out, N);
        gather_relu_kernel<<<(N + 3) / 4, 256, 0, stream>>>(rec, row_start, cnt, dinv, b1, out, N);
        gather_comb_kernel<<<(N + 3) / 4, 256, 0, stream>>>(rec, row_start, cnt, dinv, out, N);
        mm2_tiled<<<(N + 63) / 64, 256, 0, stream>>>(W2, b2, out, N);
    } else {
        // fallback: atomic scatter path (same half conventions)
        mm1_tiled<<<(N + 127) / 128, 256, 0, stream>>>(x, W1, out, N);
        zero_half_kernel<<<((N * FH) + 255) / 256, 256, 0, stream>>>(out, 0, N);
        scatter_half_kernel<<<(E + 3) / 4, 256, 0, stream>>>(src, dst, dinv, out, FH, 0, E);
        finish1_kernel<<<((N * FH) + 255) / 256, 256, 0, stream>>>(out, dinv, b1, N);
        zero_half_kernel<<<((N * FH) + 255) / 256, 256, 0, stream>>>(out, FH, N);
        scatter_half_kernel<<<(E + 3) / 4, 256, 0, stream>>>(src, dst, dinv, out, 0, FH, E);
        finish2_kernel<<<((N * FH) + 255) / 256, 256, 0, stream>>>(out, dinv, N);
        mm2_tiled<<<(N + 63) / 64, 256, 0, stream>>>(W2, b2, out, N);
    }
}